// Round 2
// baseline (430.172 us; speedup 1.0000x reference)
//
#include <hip/hip_runtime.h>

#define BB 512
#define SS 1024
#define TT 48
#define GG 32          // batches per WG: 2 groups x 16 (MFMA N)
#define CK 8           // rows per chunk
#define NSLOT 3        // LDS ring slots

typedef __attribute__((ext_vector_type(8))) short short8;
typedef __attribute__((ext_vector_type(4))) float float4v;
typedef unsigned uint2v __attribute__((ext_vector_type(2)));

// ---------- helpers ----------
__device__ __forceinline__ unsigned short f2bf(float x) {
    unsigned u = __float_as_uint(x);
    u += 0x7FFFu + ((u >> 16) & 1u);
    return (unsigned short)(u >> 16);
}
__device__ __forceinline__ unsigned pk2bf(float lo, float hi) {
#if __has_builtin(__builtin_amdgcn_cvt_pk_bf16_f32)
    typedef __bf16 bf16x2 __attribute__((ext_vector_type(2)));
    union { bf16x2 v; unsigned u; } cv;
    cv.v = __builtin_amdgcn_cvt_pk_bf16_f32(lo, hi);
    return cv.u;
#else
    return __builtin_amdgcn_perm(__float_as_uint(hi) + 0x8000u,
                                 __float_as_uint(lo) + 0x8000u, 0x07060302u);
#endif
}
__device__ __forceinline__ float wave_sum(float v) {
#pragma unroll
    for (int off = 32; off >= 1; off >>= 1) v += __shfl_xor(v, off, 64);
    return v;
}
__device__ __forceinline__ int wave_sum_i(int v) {
#pragma unroll
    for (int off = 32; off >= 1; off >>= 1) v += __shfl_xor(v, off, 64);
    return v;
}
// reduce over lanes {i, i^16, i^32, i^48} (q-groups) — VALU permlane swaps.
__device__ __forceinline__ float xgrp_max(float m) {
#if __has_builtin(__builtin_amdgcn_permlane16_swap) && __has_builtin(__builtin_amdgcn_permlane32_swap)
    uint2v a = __builtin_amdgcn_permlane16_swap(__float_as_uint(m), __float_as_uint(m), false, false);
    m = fmaxf(__uint_as_float(a[0]), __uint_as_float(a[1]));
    uint2v b = __builtin_amdgcn_permlane32_swap(__float_as_uint(m), __float_as_uint(m), false, false);
    m = fmaxf(__uint_as_float(b[0]), __uint_as_float(b[1]));
#else
    m = fmaxf(m, __shfl_xor(m, 16, 64));
    m = fmaxf(m, __shfl_xor(m, 32, 64));
#endif
    return m;
}
__device__ __forceinline__ float xgrp_sum(float m) {
#if __has_builtin(__builtin_amdgcn_permlane16_swap) && __has_builtin(__builtin_amdgcn_permlane32_swap)
    uint2v a = __builtin_amdgcn_permlane16_swap(__float_as_uint(m), __float_as_uint(m), false, false);
    m = __uint_as_float(a[0]) + __uint_as_float(a[1]);
    uint2v b = __builtin_amdgcn_permlane32_swap(__float_as_uint(m), __float_as_uint(m), false, false);
    m = __uint_as_float(b[0]) + __uint_as_float(b[1]);
#else
    m += __shfl_xor(m, 16, 64);
    m += __shfl_xor(m, 32, 64);
#endif
    return m;
}

// ---------- prep: lengths + gold-path numerator ----------
__global__ __launch_bounds__(256)
void crf_numer(const float* __restrict__ em, const int* __restrict__ tags,
               const int* __restrict__ mask, const float* __restrict__ start_tr,
               const float* __restrict__ end_tr, const float* __restrict__ trans,
               float* __restrict__ numer, int* __restrict__ lenArr) {
    const int b = blockIdx.x, tid = threadIdx.x;
    const float* emb = em + (size_t)b * SS * TT;
    const int* tg = tags + (size_t)b * SS;
    const int* mk = mask + (size_t)b * SS;
    const int s0 = tid * 4;
    const int4 t4 = *(const int4*)(tg + s0);
    const int4 m4 = *(const int4*)(mk + s0);
    const int tprev = (tid == 0) ? 0 : tg[s0 - 1];
    int cnt = (m4.x != 0) + (m4.y != 0) + (m4.z != 0) + (m4.w != 0);
    float ns = 0.f;
    if (tid > 0 && m4.x) ns += trans[tprev * TT + t4.x] + emb[(size_t)s0 * TT + t4.x];
    if (m4.y) ns += trans[t4.x * TT + t4.y] + emb[(size_t)(s0 + 1) * TT + t4.y];
    if (m4.z) ns += trans[t4.y * TT + t4.z] + emb[(size_t)(s0 + 2) * TT + t4.z];
    if (m4.w) ns += trans[t4.z * TT + t4.w] + emb[(size_t)(s0 + 3) * TT + t4.w];
    float wsum = wave_sum(ns);
    int wcnt = wave_sum_i(cnt);
    __shared__ float sf[4]; __shared__ int si[4];
    if ((tid & 63) == 0) { sf[tid >> 6] = wsum; si[tid >> 6] = wcnt; }
    __syncthreads();
    if (tid == 0) {
        float tot = sf[0] + sf[1] + sf[2] + sf[3];
        int L = si[0] + si[1] + si[2] + si[3];
        int t0 = tg[0];
        tot += start_tr[t0] + emb[t0] + end_tr[tg[L - 1]];
        numer[b] = tot;
        lenArr[b] = L;
    }
}

// ---------- main: 4 waves/WG. wave0 = consumer (own SIMD), waves1-3 producers ----------
// TWO independent 16-batch recurrences (groups A,B) interleaved in the consumer
// wave: while group A's MFMA chain is in latency, group B's pack/MFMA issues.
// Ring entry (slot,u,j,g,lane): float4 = exp(em) for states j*16+(lane>>4)*4..+3,
// batch = wgbase + g*16 + (lane&15). Producers use identical lane mapping.
__global__ __launch_bounds__(256, 1)
void crf_fwd(const float* __restrict__ em, const float* __restrict__ start_tr,
             const float* __restrict__ end_tr, const float* __restrict__ trans,
             const int* __restrict__ lenArr, float* __restrict__ denomArr) {
    __shared__ float4v ring[NSLOT * CK * 3 * 2 * 64];   // 147456 B (<= 160 KiB LDS)

    const int tid = threadIdx.x;
    const int wave = tid >> 6, lane = tid & 63;
    const int wgbase = blockIdx.x * GG;
    const float4v Zv = {0.f, 0.f, 0.f, 0.f};

    if (wave == 0) {
        // ================= CONSUMER =================
        __builtin_amdgcn_s_setprio(1);
        const int n = lane & 15, q = lane >> 4;
        const int bbA = wgbase + n, bbB = wgbase + 16 + n;

        // A[m=s_out][k-slot(s_in)] = exp(trans[s_out][s_in]) — shared by both groups
        short8 afr[3][2];
#pragma unroll
        for (int mt = 0; mt < 3; ++mt) {
            const int so = mt * 16 + n;
#pragma unroll
            for (int kt = 0; kt < 2; ++kt) {
                short8 a;
#pragma unroll
                for (int i = 0; i < 8; ++i) {
                    int si_;
                    if (kt == 0) si_ = (i < 4) ? (q * 4 + i) : (16 + q * 4 + (i - 4));
                    else         si_ = (i < 4) ? (32 + q * 4 + i) : -1;
                    a[i] = (si_ >= 0) ? (short)f2bf(__expf(trans[so * TT + si_])) : (short)0;
                }
                afr[mt][kt] = a;
            }
        }

        // init p = exp(start) * exp(em row0)   (state t=0)
        const float* em0A = em + (size_t)bbA * SS * TT + q * 4;
        const float* em0B = em + (size_t)bbB * SS * TT + q * 4;
        float4v pA[3], pB[3];
#pragma unroll
        for (int mt = 0; mt < 3; ++mt) {
            float4v vA = *(const float4v*)(em0A + mt * 16);
            float4v vB = *(const float4v*)(em0B + mt * 16);
            const int sb = mt * 16 + q * 4;
#pragma unroll
            for (int r = 0; r < 4; ++r) {
                float st = start_tr[sb + r];
                pA[mt][r] = __expf(st + vA[r]);
                pB[mt][r] = __expf(st + vB[r]);
            }
        }

        const int lenA = lenArr[bbA], lenB = lenArr[bbB];
        int Lmax = lenA > lenB ? lenA : lenB;
#pragma unroll
        for (int off = 1; off < 64; off <<= 1) {
            int o = __shfl_xor(Lmax, off, 64);
            Lmax = Lmax > o ? Lmax : o;
        }
        const int P = (Lmax + 6) >> 3;   // ceil((Lmax-1)/8)

        float4v dcA[3], dcB[3];
        {
            const bool c0A = (lenA == 1), c0B = (lenB == 1);
#pragma unroll
            for (int mt = 0; mt < 3; ++mt) {
                dcA[mt] = c0A ? pA[mt] : Zv;
                dcB[mt] = c0B ? pB[mt] : Zv;
            }
        }
        float lcapA = 0.f, lcapB = 0.f, lsA = 0.f, lsB = 0.f;

        for (int pp = -3; pp < P; ++pp) {
            if (pp >= 0) {
                const float4v* rp = ring + (size_t)(pp % NSLOT) * (CK * 3 * 2 * 64) + lane;
                float4v cA0 = rp[0],  cA1 = rp[128], cA2 = rp[256];
                float4v cB0 = rp[64], cB1 = rp[192], cB2 = rp[320];
                const int lo = 8 * pp + 2, hi = 8 * pp + 9;
                const bool any =
                    __ballot(((lenA >= lo) & (lenA <= hi)) | ((lenB >= lo) & (lenB <= hi))) != 0ull;
#pragma unroll
                for (int u = 0; u < 8; ++u) {
                    // pack B operands for both groups (chain heads)
                    union { short8 v; unsigned w[4]; } BA0, BA1, BB0, BB1;
                    BA0.w[0] = pk2bf(pA[0][0], pA[0][1]); BA0.w[1] = pk2bf(pA[0][2], pA[0][3]);
                    BA0.w[2] = pk2bf(pA[1][0], pA[1][1]); BA0.w[3] = pk2bf(pA[1][2], pA[1][3]);
                    BA1.w[0] = pk2bf(pA[2][0], pA[2][1]); BA1.w[1] = pk2bf(pA[2][2], pA[2][3]);
                    BA1.w[2] = 0u; BA1.w[3] = 0u;
                    BB0.w[0] = pk2bf(pB[0][0], pB[0][1]); BB0.w[1] = pk2bf(pB[0][2], pB[0][3]);
                    BB0.w[2] = pk2bf(pB[1][0], pB[1][1]); BB0.w[3] = pk2bf(pB[1][2], pB[1][3]);
                    BB1.w[0] = pk2bf(pB[2][0], pB[2][1]); BB1.w[1] = pk2bf(pB[2][2], pB[2][3]);
                    BB1.w[2] = 0u; BB1.w[3] = 0u;
                    // chained-accumulate MFMA pairs (round-0 structure), A and B interleaved
                    float4v rA0 = __builtin_amdgcn_mfma_f32_16x16x32_bf16(afr[0][0], BA0.v, Zv, 0, 0, 0);
                    float4v rB0 = __builtin_amdgcn_mfma_f32_16x16x32_bf16(afr[0][0], BB0.v, Zv, 0, 0, 0);
                    float4v rA1 = __builtin_amdgcn_mfma_f32_16x16x32_bf16(afr[1][0], BA0.v, Zv, 0, 0, 0);
                    float4v rB1 = __builtin_amdgcn_mfma_f32_16x16x32_bf16(afr[1][0], BB0.v, Zv, 0, 0, 0);
                    float4v rA2 = __builtin_amdgcn_mfma_f32_16x16x32_bf16(afr[2][0], BA0.v, Zv, 0, 0, 0);
                    float4v rB2 = __builtin_amdgcn_mfma_f32_16x16x32_bf16(afr[2][0], BB0.v, Zv, 0, 0, 0);
                    rA0 = __builtin_amdgcn_mfma_f32_16x16x32_bf16(afr[0][1], BA1.v, rA0, 0, 0, 0);
                    rB0 = __builtin_amdgcn_mfma_f32_16x16x32_bf16(afr[0][1], BB1.v, rB0, 0, 0, 0);
                    rA1 = __builtin_amdgcn_mfma_f32_16x16x32_bf16(afr[1][1], BA1.v, rA1, 0, 0, 0);
                    rB1 = __builtin_amdgcn_mfma_f32_16x16x32_bf16(afr[1][1], BB1.v, rB1, 0, 0, 0);
                    rA2 = __builtin_amdgcn_mfma_f32_16x16x32_bf16(afr[2][1], BA1.v, rA2, 0, 0, 0);
                    rB2 = __builtin_amdgcn_mfma_f32_16x16x32_bf16(afr[2][1], BB1.v, rB2, 0, 0, 0);
                    // shadow work: prefetch next row's emissions (f32, no unpack needed)
                    float4v nA0, nA1, nA2, nB0, nB1, nB2;
                    if (u < 7) {
                        nA0 = rp[(u + 1) * 384];       nA1 = rp[(u + 1) * 384 + 128];
                        nA2 = rp[(u + 1) * 384 + 256];
                        nB0 = rp[(u + 1) * 384 + 64];  nB1 = rp[(u + 1) * 384 + 192];
                        nB2 = rp[(u + 1) * 384 + 320];
                    }
                    // p_t = (M @ p_{t-1}) * exp(em_t)   (vector elementwise)
                    pA[0] = rA0 * cA0; pA[1] = rA1 * cA1; pA[2] = rA2 * cA2;
                    pB[0] = rB0 * cB0; pB[1] = rB1 * cB1; pB[2] = rB2 * cB2;
                    // capture final live state (t == len-1); skipped in ~87% of chunks
                    if (any) {
                        const bool ccA = (lenA == 8 * pp + u + 2);
                        const bool ccB = (lenB == 8 * pp + u + 2);
#pragma unroll
                        for (int mt = 0; mt < 3; ++mt) {
                            dcA[mt] = ccA ? pA[mt] : dcA[mt];
                            dcB[mt] = ccB ? pB[mt] : dcB[mt];
                        }
                        lcapA = ccA ? lsA : lcapA;
                        lcapB = ccB ? lsB : lcapB;
                    }
                    cA0 = nA0; cA1 = nA1; cA2 = nA2;
                    cB0 = nB0; cB1 = nB1; cB2 = nB2;
                    if (u == 7) {   // renorm once per chunk, per group
                        float mA = fmaxf(fmaxf(pA[0][0], pA[0][1]), fmaxf(pA[0][2], pA[0][3]));
                        mA = fmaxf(mA, fmaxf(fmaxf(pA[1][0], pA[1][1]), fmaxf(pA[1][2], pA[1][3])));
                        mA = fmaxf(mA, fmaxf(fmaxf(pA[2][0], pA[2][1]), fmaxf(pA[2][2], pA[2][3])));
                        float mB = fmaxf(fmaxf(pB[0][0], pB[0][1]), fmaxf(pB[0][2], pB[0][3]));
                        mB = fmaxf(mB, fmaxf(fmaxf(pB[1][0], pB[1][1]), fmaxf(pB[1][2], pB[1][3])));
                        mB = fmaxf(mB, fmaxf(fmaxf(pB[2][0], pB[2][1]), fmaxf(pB[2][2], pB[2][3])));
                        mA = fmaxf(xgrp_max(mA), 1e-30f);
                        mB = fmaxf(xgrp_max(mB), 1e-30f);
                        lsA += __logf(mA);
                        lsB += __logf(mB);
                        const float rmA = __builtin_amdgcn_rcpf(mA);
                        const float rmB = __builtin_amdgcn_rcpf(mB);
                        pA[0] *= rmA; pA[1] *= rmA; pA[2] *= rmA;
                        pB[0] *= rmB; pB[1] *= rmB; pB[2] *= rmB;
                    }
                }
            }
            __builtin_amdgcn_s_barrier();
        }

        // epilogue (both groups)
        float peA = 0.f, peB = 0.f;
#pragma unroll
        for (int mt = 0; mt < 3; ++mt) {
            const int sb = mt * 16 + q * 4;
#pragma unroll
            for (int r = 0; r < 4; ++r) {
                float ee = __expf(end_tr[sb + r]);
                peA = fmaf(dcA[mt][r], ee, peA);
                peB = fmaf(dcB[mt][r], ee, peB);
            }
        }
        peA = xgrp_sum(peA);
        peB = xgrp_sum(peB);
        if (lane < 16) {
            denomArr[bbA] = lcapA + __logf(peA);
            denomArr[bbB] = lcapB + __logf(peB);
        }

    } else {
        // ================= PRODUCERS (waves 1..3) =================
        // wave w owns chunks c with c % 3 == w. Per chunk c:
        //   period c-3: load group-A emissions (24 float4 -> buf)
        //   period c-2: convert+write group A; load group-B into same buf regs
        //   period c-1: convert+write group B
        const int w = wave - 1;
        const int nb = lane & 15, q4 = lane >> 4;   // SAME mapping as consumer
        const int bbA = wgbase + nb, bbB = wgbase + 16 + nb;
        const int lenA_v = lenArr[bbA], lenB_v = lenArr[bbB];
        int Lmax = lenA_v > lenB_v ? lenA_v : lenB_v;
#pragma unroll
        for (int off = 1; off < 64; off <<= 1) {
            int o = __shfl_xor(Lmax, off, 64);
            Lmax = Lmax > o ? Lmax : o;
        }
        const int P = (Lmax + 6) >> 3;

        const float* emA = em + (size_t)bbA * SS * TT + q4 * 4;
        const float* emB = em + (size_t)bbB * SS * TT + q4 * 4;
        float4v buf[24];   // constant indices -> registers

        for (int pp = -3; pp < P; ++pp) {
            const int ci = pp + 3;               // load group A of chunk ci
            if (ci < P && ci % 3 == w) {
#pragma unroll
                for (int kk = 0; kk < 24; ++kk) {
                    const int u = kk / 3, j = kk % 3;
                    int t = 1 + 8 * ci + u; t = t < SS ? t : SS - 1;
                    buf[kk] = *(const float4v*)(emA + (size_t)t * TT + j * 16);
                }
            }
            const int ca = pp + 2;               // convert A, then load B (reuses buf)
            if (ca >= 0 && ca < P && ca % 3 == w) {
                float4v* wp = ring + (size_t)(ca % NSLOT) * (CK * 3 * 2 * 64) + lane;
#pragma unroll
                for (int kk = 0; kk < 24; ++kk) {
                    const int u = kk / 3, j = kk % 3;
                    const int t = 1 + 8 * ca + u;
                    float4v v = buf[kk];
                    float4v o;
                    o[0] = __expf(v[0]); o[1] = __expf(v[1]);
                    o[2] = __expf(v[2]); o[3] = __expf(v[3]);
                    o = (t < lenA_v) ? o : Zv;
                    wp[(size_t)(u * 3 + j) * 128] = o;
                }
#pragma unroll
                for (int kk = 0; kk < 24; ++kk) {
                    const int u = kk / 3, j = kk % 3;
                    int t = 1 + 8 * ca + u; t = t < SS ? t : SS - 1;
                    buf[kk] = *(const float4v*)(emB + (size_t)t * TT + j * 16);
                }
            }
            const int cb = pp + 1;               // convert B
            if (cb >= 0 && cb < P && cb % 3 == w) {
                float4v* wp = ring + (size_t)(cb % NSLOT) * (CK * 3 * 2 * 64) + 64 + lane;
#pragma unroll
                for (int kk = 0; kk < 24; ++kk) {
                    const int u = kk / 3, j = kk % 3;
                    const int t = 1 + 8 * cb + u;
                    float4v v = buf[kk];
                    float4v o;
                    o[0] = __expf(v[0]); o[1] = __expf(v[1]);
                    o[2] = __expf(v[2]); o[3] = __expf(v[3]);
                    o = (t < lenB_v) ? o : Zv;
                    wp[(size_t)(u * 3 + j) * 128] = o;
                }
            }
            __builtin_amdgcn_s_waitcnt(0xC07F);  // lgkmcnt(0) only; vmcnt stays in flight
            __builtin_amdgcn_s_barrier();
        }
    }
}

__global__ __launch_bounds__(64)
void crf_reduce(const float* __restrict__ denom, const float* __restrict__ numer,
                float* __restrict__ out) {
    int lane = threadIdx.x;
    float s = 0.f;
    for (int i = lane; i < BB; i += 64) s += denom[i] - numer[i];
    s = wave_sum(s);
    if (lane == 0) out[0] = s * (1.0f / (float)BB);
}

extern "C" void kernel_launch(void* const* d_in, const int* in_sizes, int n_in,
                              void* d_out, int out_size, void* d_ws, size_t ws_size,
                              hipStream_t stream) {
    const float* emissions = (const float*)d_in[0];
    const int*   tags      = (const int*)d_in[1];
    const int*   mask      = (const int*)d_in[2];
    const float* start_tr  = (const float*)d_in[3];
    const float* end_tr    = (const float*)d_in[4];
    const float* trans     = (const float*)d_in[5];

    char* ws = (char*)d_ws;
    float* denom = (float*)ws;               // 512 f32
    float* numer = (float*)(ws + 2048);      // 512 f32
    int*   lenA  = (int*)(ws + 4096);        // 512 i32

    crf_numer<<<BB, 256, 0, stream>>>(emissions, tags, mask, start_tr, end_tr,
                                      trans, numer, lenA);
    crf_fwd<<<BB / GG, 256, 0, stream>>>(emissions, start_tr, end_tr, trans,
                                         lenA, denom);
    crf_reduce<<<1, 64, 0, stream>>>(denom, numer, (float*)d_out);
}

// Round 3
// 324.451 us; speedup vs baseline: 1.3258x; 1.3258x over previous
//
#include <hip/hip_runtime.h>

#define BB 512
#define SS 1024
#define TT 48
#define GG 16          // batches per WG (MFMA N)
#define CK 8           // rows per chunk
#define NSLOT 5        // LDS ring slots

typedef __attribute__((ext_vector_type(8))) short short8;
typedef __attribute__((ext_vector_type(4))) float float4v;
typedef unsigned uint2v __attribute__((ext_vector_type(2)));

// ---------- helpers ----------
__device__ __forceinline__ unsigned short f2bf(float x) {
    unsigned u = __float_as_uint(x);
    u += 0x7FFFu + ((u >> 16) & 1u);
    return (unsigned short)(u >> 16);
}
__device__ __forceinline__ unsigned pk2bf(float lo, float hi) {
#if __has_builtin(__builtin_amdgcn_cvt_pk_bf16_f32)
    typedef __bf16 bf16x2 __attribute__((ext_vector_type(2)));
    union { bf16x2 v; unsigned u; } cv;
    cv.v = __builtin_amdgcn_cvt_pk_bf16_f32(lo, hi);
    return cv.u;
#else
    return __builtin_amdgcn_perm(__float_as_uint(hi) + 0x8000u,
                                 __float_as_uint(lo) + 0x8000u, 0x07060302u);
#endif
}
__device__ __forceinline__ float bflo(unsigned u) { return __uint_as_float(u << 16); }
__device__ __forceinline__ float bfhi(unsigned u) { return __uint_as_float(u & 0xFFFF0000u); }
__device__ __forceinline__ float wave_sum(float v) {
#pragma unroll
    for (int off = 32; off >= 1; off >>= 1) v += __shfl_xor(v, off, 64);
    return v;
}
__device__ __forceinline__ int wave_sum_i(int v) {
#pragma unroll
    for (int off = 32; off >= 1; off >>= 1) v += __shfl_xor(v, off, 64);
    return v;
}
// reduce over lanes {i, i^16, i^32, i^48} — VALU permlane swaps, no LDS path.
__device__ __forceinline__ float xgrp_max(float m) {
#if __has_builtin(__builtin_amdgcn_permlane16_swap) && __has_builtin(__builtin_amdgcn_permlane32_swap)
    uint2v a = __builtin_amdgcn_permlane16_swap(__float_as_uint(m), __float_as_uint(m), false, false);
    m = fmaxf(__uint_as_float(a[0]), __uint_as_float(a[1]));
    uint2v b = __builtin_amdgcn_permlane32_swap(__float_as_uint(m), __float_as_uint(m), false, false);
    m = fmaxf(__uint_as_float(b[0]), __uint_as_float(b[1]));
#else
    m = fmaxf(m, __shfl_xor(m, 16, 64));
    m = fmaxf(m, __shfl_xor(m, 32, 64));
#endif
    return m;
}
__device__ __forceinline__ float xgrp_sum(float m) {
#if __has_builtin(__builtin_amdgcn_permlane16_swap) && __has_builtin(__builtin_amdgcn_permlane32_swap)
    uint2v a = __builtin_amdgcn_permlane16_swap(__float_as_uint(m), __float_as_uint(m), false, false);
    m = __uint_as_float(a[0]) + __uint_as_float(a[1]);
    uint2v b = __builtin_amdgcn_permlane32_swap(__float_as_uint(m), __float_as_uint(m), false, false);
    m = __uint_as_float(b[0]) + __uint_as_float(b[1]);
#else
    m += __shfl_xor(m, 16, 64);
    m += __shfl_xor(m, 32, 64);
#endif
    return m;
}

// ---------- prep: lengths + gold-path numerator ----------
__global__ __launch_bounds__(256)
void crf_numer(const float* __restrict__ em, const int* __restrict__ tags,
               const int* __restrict__ mask, const float* __restrict__ start_tr,
               const float* __restrict__ end_tr, const float* __restrict__ trans,
               float* __restrict__ numer, int* __restrict__ lenArr) {
    const int b = blockIdx.x, tid = threadIdx.x;
    const float* emb = em + (size_t)b * SS * TT;
    const int* tg = tags + (size_t)b * SS;
    const int* mk = mask + (size_t)b * SS;
    const int s0 = tid * 4;
    const int4 t4 = *(const int4*)(tg + s0);
    const int4 m4 = *(const int4*)(mk + s0);
    const int tprev = (tid == 0) ? 0 : tg[s0 - 1];
    int cnt = (m4.x != 0) + (m4.y != 0) + (m4.z != 0) + (m4.w != 0);
    float ns = 0.f;
    if (tid > 0 && m4.x) ns += trans[tprev * TT + t4.x] + emb[(size_t)s0 * TT + t4.x];
    if (m4.y) ns += trans[t4.x * TT + t4.y] + emb[(size_t)(s0 + 1) * TT + t4.y];
    if (m4.z) ns += trans[t4.y * TT + t4.z] + emb[(size_t)(s0 + 2) * TT + t4.z];
    if (m4.w) ns += trans[t4.z * TT + t4.w] + emb[(size_t)(s0 + 3) * TT + t4.w];
    float wsum = wave_sum(ns);
    int wcnt = wave_sum_i(cnt);
    __shared__ float sf[4]; __shared__ int si[4];
    if ((tid & 63) == 0) { sf[tid >> 6] = wsum; si[tid >> 6] = wcnt; }
    __syncthreads();
    if (tid == 0) {
        float tot = sf[0] + sf[1] + sf[2] + sf[3];
        int L = si[0] + si[1] + si[2] + si[3];
        int t0 = tg[0];
        tot += start_tr[t0] + emb[t0] + end_tr[tg[L - 1]];
        numer[b] = tot;
        lenArr[b] = L;
    }
}

// ---------- main: 5 waves/WG. wave0 = MFMA consumer; waves1-4 = 2 producer teams ----------
// LDS ring entry (slot, row u, section j, entry e): e == consumer lane (q*16+n),
// bf16x2 pair = states {j*16+q*4 .. +3} of batch n. Producers use the SAME lane
// mapping (nb=lane&15, q4=lane>>4) so both read & write at entry==lane: conflict-free.
__global__ __launch_bounds__(320, 1)
void crf_fwd(const float* __restrict__ em, const float* __restrict__ start_tr,
             const float* __restrict__ end_tr, const float* __restrict__ trans,
             const int* __restrict__ lenArr, float* __restrict__ denomArr) {
    __shared__ uint2 ring[NSLOT * CK * 3 * 64];   // 61440 B

    const int tid = threadIdx.x;
    const int wave = tid >> 6, lane = tid & 63;
    const int wgbase = blockIdx.x * GG;

    if (wave == 0) {
        // ================= CONSUMER =================
        const int n = lane & 15, q = lane >> 4;
        const int bb = wgbase + n;

        // A[m=s_out][k-slot(s_in)] = exp(trans[s_out][s_in])
        short8 afr[3][2];
#pragma unroll
        for (int mt = 0; mt < 3; ++mt) {
            const int so = mt * 16 + n;
#pragma unroll
            for (int kt = 0; kt < 2; ++kt) {
                short8 a;
#pragma unroll
                for (int i = 0; i < 8; ++i) {
                    int si_;
                    if (kt == 0) si_ = (i < 4) ? (q * 4 + i) : (16 + q * 4 + (i - 4));
                    else         si_ = (i < 4) ? (32 + q * 4 + i) : -1;
                    a[i] = (si_ >= 0) ? (short)f2bf(__expf(trans[so * TT + si_])) : (short)0;
                }
                afr[mt][kt] = a;
            }
        }

        // init p = exp(start) * exp(em row0)
        const float* em0 = em + (size_t)bb * SS * TT + q * 4;
        float p[3][4];
#pragma unroll
        for (int mt = 0; mt < 3; ++mt) {
            float4 v = *(const float4*)(em0 + mt * 16);
            int sb = mt * 16 + q * 4;
            p[mt][0] = __expf(start_tr[sb + 0] + v.x);
            p[mt][1] = __expf(start_tr[sb + 1] + v.y);
            p[mt][2] = __expf(start_tr[sb + 2] + v.z);
            p[mt][3] = __expf(start_tr[sb + 3] + v.w);
        }

        const int len = lenArr[bb];
        int Lmax = len;
#pragma unroll
        for (int off = 1; off < 64; off <<= 1) {
            int o = __shfl_xor(Lmax, off, 64);
            Lmax = Lmax > o ? Lmax : o;
        }
        const int P = (Lmax + 6) >> 3;   // ceil((Lmax-1)/8)

        bool cc0 = (len == 1);
        float dc[3][4];
#pragma unroll
        for (int mt = 0; mt < 3; ++mt)
#pragma unroll
            for (int r = 0; r < 4; ++r) dc[mt][r] = cc0 ? p[mt][r] : 0.f;
        float lcap = 0.f, logscale = 0.f;
        const float4v Z = {0.f, 0.f, 0.f, 0.f};

        for (int pp = -3; pp < P; ++pp) {
            if (pp >= 0) {
                const uint2* rp = &ring[(pp % NSLOT) * (CK * 3 * 64) + lane];
                // ---- chunk prefetch: ALL 24 emission pairs -> registers, one wait.
                // Inner 8-step loop then has ZERO LDS ops (H4: removes per-step
                // lgkmcnt stalls from the serial critical path).
                uint2 emch[8][3];
#pragma unroll
                for (int u = 0; u < 8; ++u) {
#pragma unroll
                    for (int j = 0; j < 3; ++j)
                        emch[u][j] = rp[u * 192 + j * 64];
                }
                // capture can only trigger if some lane's len is in this chunk
                const int lo = 8 * pp + 2, hi = 8 * pp + 9;
                const bool any = __ballot((len >= lo) & (len <= hi)) != 0ull;
#pragma unroll
                for (int u = 0; u < 8; ++u) {
                    union { short8 v; unsigned w[4]; } B0, B1;
                    B0.w[0] = pk2bf(p[0][0], p[0][1]); B0.w[1] = pk2bf(p[0][2], p[0][3]);
                    B0.w[2] = pk2bf(p[1][0], p[1][1]); B0.w[3] = pk2bf(p[1][2], p[1][3]);
                    B1.w[0] = pk2bf(p[2][0], p[2][1]); B1.w[1] = pk2bf(p[2][2], p[2][3]);
                    B1.w[2] = 0u; B1.w[3] = 0u;
                    float4v A0 = __builtin_amdgcn_mfma_f32_16x16x32_bf16(afr[0][0], B0.v, Z, 0, 0, 0);
                    float4v A1 = __builtin_amdgcn_mfma_f32_16x16x32_bf16(afr[1][0], B0.v, Z, 0, 0, 0);
                    float4v A2 = __builtin_amdgcn_mfma_f32_16x16x32_bf16(afr[2][0], B0.v, Z, 0, 0, 0);
                    A0 = __builtin_amdgcn_mfma_f32_16x16x32_bf16(afr[0][1], B1.v, A0, 0, 0, 0);
                    A1 = __builtin_amdgcn_mfma_f32_16x16x32_bf16(afr[1][1], B1.v, A1, 0, 0, 0);
                    A2 = __builtin_amdgcn_mfma_f32_16x16x32_bf16(afr[2][1], B1.v, A2, 0, 0, 0);
                    const uint2 c0 = emch[u][0], c1 = emch[u][1], c2v = emch[u][2];
                    p[0][0] = A0[0] * bflo(c0.x); p[0][1] = A0[1] * bfhi(c0.x);
                    p[0][2] = A0[2] * bflo(c0.y); p[0][3] = A0[3] * bfhi(c0.y);
                    p[1][0] = A1[0] * bflo(c1.x); p[1][1] = A1[1] * bfhi(c1.x);
                    p[1][2] = A1[2] * bflo(c1.y); p[1][3] = A1[3] * bfhi(c1.y);
                    p[2][0] = A2[0] * bflo(c2v.x); p[2][1] = A2[1] * bfhi(c2v.x);
                    p[2][2] = A2[2] * bflo(c2v.y); p[2][3] = A2[3] * bfhi(c2v.y);
                    if (any) {
                        bool cc = (len == 8 * pp + u + 2);   // t = 1 + 8*pp + u
#pragma unroll
                        for (int mt = 0; mt < 3; ++mt)
#pragma unroll
                            for (int r = 0; r < 4; ++r) dc[mt][r] = cc ? p[mt][r] : dc[mt][r];
                        lcap = cc ? logscale : lcap;
                    }
                    if (u == 7) {   // renorm once per chunk (VALU-only cross-lane max)
                        float m = fmaxf(fmaxf(p[0][0], p[0][1]), fmaxf(p[0][2], p[0][3]));
                        m = fmaxf(m, fmaxf(fmaxf(p[1][0], p[1][1]), fmaxf(p[1][2], p[1][3])));
                        m = fmaxf(m, fmaxf(fmaxf(p[2][0], p[2][1]), fmaxf(p[2][2], p[2][3])));
                        m = fmaxf(xgrp_max(m), 1e-30f);
                        logscale += __logf(m);
                        float rm = __builtin_amdgcn_rcpf(m);
#pragma unroll
                        for (int mt = 0; mt < 3; ++mt)
#pragma unroll
                            for (int r = 0; r < 4; ++r) p[mt][r] *= rm;
                    }
                }
            }
            __builtin_amdgcn_s_barrier();
        }

        // epilogue
        float pe = 0.f;
#pragma unroll
        for (int mt = 0; mt < 3; ++mt) {
            int sb = mt * 16 + q * 4;
            pe = fmaf(dc[mt][0], __expf(end_tr[sb + 0]), pe);
            pe = fmaf(dc[mt][1], __expf(end_tr[sb + 1]), pe);
            pe = fmaf(dc[mt][2], __expf(end_tr[sb + 2]), pe);
            pe = fmaf(dc[mt][3], __expf(end_tr[sb + 3]), pe);
        }
        pe = xgrp_sum(pe);
        if (lane < 16) denomArr[bb] = lcap + __logf(pe);

    } else {
        // ================= PRODUCERS (waves 1..4, two teams) =================
        const int T = (wave - 1) >> 1;       // team parity: chunks c with (c&1)==T
        const int sub = (wave - 1) & 1;      // items i = sub*12 .. sub*12+11
        const int nb = lane & 15, q4 = lane >> 4;   // SAME mapping as consumer
        const int bb = wgbase + nb;
        const int len_v = lenArr[bb];
        int Lmax = len_v;
#pragma unroll
        for (int off = 1; off < 64; off <<= 1) {
            int o = __shfl_xor(Lmax, off, 64);
            Lmax = Lmax > o ? Lmax : o;
        }
        const int P = (Lmax + 6) >> 3;

        const float* emP = em + (size_t)bb * SS * TT + q4 * 4;
        float4 buf[12];   // single named buffer, constant indices -> registers

        for (int pp = -3; pp < P; ++pp) {
            int cv = pp + 1;                 // chunk to convert (loaded 2 periods ago)
            if (cv >= 0 && cv < P && (cv & 1) == T) {
                uint2* wp = &ring[(cv % NSLOT) * (CK * 3 * 64) + lane];
#pragma unroll
                for (int k = 0; k < 12; ++k) {
                    const int i = sub * 12 + k, u = i / 3, j = i % 3;
                    int t = 1 + 8 * cv + u;
                    bool live = t < len_v;
                    float4 v = buf[k];
                    unsigned ox = pk2bf(__expf(v.x), __expf(v.y));
                    unsigned oy = pk2bf(__expf(v.z), __expf(v.w));
                    uint2 o;
                    o.x = live ? ox : 0u;
                    o.y = live ? oy : 0u;
                    wp[u * 192 + j * 64] = o;
                }
            }
            int ci = pp + 3;                 // chunk to issue loads for (same parity)
            if (ci < P && (ci & 1) == T) {
#pragma unroll
                for (int k = 0; k < 12; ++k) {
                    const int i = sub * 12 + k, u = i / 3, j = i % 3;
                    int t = 1 + 8 * ci + u; t = t < SS ? t : SS - 1;
                    buf[k] = *(const float4*)(emP + (size_t)t * TT + j * 16);
                }
            }
            __builtin_amdgcn_s_waitcnt(0xC07F);  // lgkmcnt(0) only; vmcnt stays in flight
            __builtin_amdgcn_s_barrier();
        }
    }
}

__global__ __launch_bounds__(64)
void crf_reduce(const float* __restrict__ denom, const float* __restrict__ numer,
                float* __restrict__ out) {
    int lane = threadIdx.x;
    float s = 0.f;
    for (int i = lane; i < BB; i += 64) s += denom[i] - numer[i];
    s = wave_sum(s);
    if (lane == 0) out[0] = s * (1.0f / (float)BB);
}

extern "C" void kernel_launch(void* const* d_in, const int* in_sizes, int n_in,
                              void* d_out, int out_size, void* d_ws, size_t ws_size,
                              hipStream_t stream) {
    const float* emissions = (const float*)d_in[0];
    const int*   tags      = (const int*)d_in[1];
    const int*   mask      = (const int*)d_in[2];
    const float* start_tr  = (const float*)d_in[3];
    const float* end_tr    = (const float*)d_in[4];
    const float* trans     = (const float*)d_in[5];

    char* ws = (char*)d_ws;
    float* denom = (float*)ws;               // 512 f32
    float* numer = (float*)(ws + 2048);      // 512 f32
    int*   lenA  = (int*)(ws + 4096);        // 512 i32

    crf_numer<<<BB, 256, 0, stream>>>(emissions, tags, mask, start_tr, end_tr,
                                      trans, numer, lenA);
    crf_fwd<<<BB / GG, 320, 0, stream>>>(emissions, start_tr, end_tr, trans,
                                         lenA, denom);
    crf_reduce<<<1, 64, 0, stream>>>(denom, numer, (float*)d_out);
}

// Round 4
// 299.275 us; speedup vs baseline: 1.4374x; 1.0841x over previous
//
#include <hip/hip_runtime.h>

#define BB 512
#define SS 1024
#define TT 48
#define GG 16          // batches per WG (MFMA N)
#define CK 8           // rows per chunk
#define NSLOT 4        // LDS ring slots (f32 ring: 4*8*3*64*16B = 98304 B)

typedef __attribute__((ext_vector_type(8))) short short8;
typedef __attribute__((ext_vector_type(4))) float float4v;
typedef unsigned uint2v __attribute__((ext_vector_type(2)));

// ---------- helpers ----------
__device__ __forceinline__ unsigned short f2bf(float x) {
    unsigned u = __float_as_uint(x);
    u += 0x7FFFu + ((u >> 16) & 1u);
    return (unsigned short)(u >> 16);
}
__device__ __forceinline__ unsigned pk2bf(float lo, float hi) {
#if __has_builtin(__builtin_amdgcn_cvt_pk_bf16_f32)
    typedef __bf16 bf16x2 __attribute__((ext_vector_type(2)));
    union { bf16x2 v; unsigned u; } cv;
    cv.v = __builtin_amdgcn_cvt_pk_bf16_f32(lo, hi);
    return cv.u;
#else
    return __builtin_amdgcn_perm(__float_as_uint(hi) + 0x8000u,
                                 __float_as_uint(lo) + 0x8000u, 0x07060302u);
#endif
}
__device__ __forceinline__ float wave_sum(float v) {
#pragma unroll
    for (int off = 32; off >= 1; off >>= 1) v += __shfl_xor(v, off, 64);
    return v;
}
__device__ __forceinline__ int wave_sum_i(int v) {
#pragma unroll
    for (int off = 32; off >= 1; off >>= 1) v += __shfl_xor(v, off, 64);
    return v;
}
// reduce over lanes {i, i^16, i^32, i^48} — VALU permlane swaps, no LDS path.
__device__ __forceinline__ float xgrp_max(float m) {
#if __has_builtin(__builtin_amdgcn_permlane16_swap) && __has_builtin(__builtin_amdgcn_permlane32_swap)
    uint2v a = __builtin_amdgcn_permlane16_swap(__float_as_uint(m), __float_as_uint(m), false, false);
    m = fmaxf(__uint_as_float(a[0]), __uint_as_float(a[1]));
    uint2v b = __builtin_amdgcn_permlane32_swap(__float_as_uint(m), __float_as_uint(m), false, false);
    m = fmaxf(__uint_as_float(b[0]), __uint_as_float(b[1]));
#else
    m = fmaxf(m, __shfl_xor(m, 16, 64));
    m = fmaxf(m, __shfl_xor(m, 32, 64));
#endif
    return m;
}
__device__ __forceinline__ float xgrp_sum(float m) {
#if __has_builtin(__builtin_amdgcn_permlane16_swap) && __has_builtin(__builtin_amdgcn_permlane32_swap)
    uint2v a = __builtin_amdgcn_permlane16_swap(__float_as_uint(m), __float_as_uint(m), false, false);
    m = __uint_as_float(a[0]) + __uint_as_float(a[1]);
    uint2v b = __builtin_amdgcn_permlane32_swap(__float_as_uint(m), __float_as_uint(m), false, false);
    m = __uint_as_float(b[0]) + __uint_as_float(b[1]);
#else
    m += __shfl_xor(m, 16, 64);
    m += __shfl_xor(m, 32, 64);
#endif
    return m;
}

// ---------- prep: lengths + gold-path numerator ----------
__global__ __launch_bounds__(256)
void crf_numer(const float* __restrict__ em, const int* __restrict__ tags,
               const int* __restrict__ mask, const float* __restrict__ start_tr,
               const float* __restrict__ end_tr, const float* __restrict__ trans,
               float* __restrict__ numer, int* __restrict__ lenArr) {
    const int b = blockIdx.x, tid = threadIdx.x;
    const float* emb = em + (size_t)b * SS * TT;
    const int* tg = tags + (size_t)b * SS;
    const int* mk = mask + (size_t)b * SS;
    const int s0 = tid * 4;
    const int4 t4 = *(const int4*)(tg + s0);
    const int4 m4 = *(const int4*)(mk + s0);
    const int tprev = (tid == 0) ? 0 : tg[s0 - 1];
    int cnt = (m4.x != 0) + (m4.y != 0) + (m4.z != 0) + (m4.w != 0);
    float ns = 0.f;
    if (tid > 0 && m4.x) ns += trans[tprev * TT + t4.x] + emb[(size_t)s0 * TT + t4.x];
    if (m4.y) ns += trans[t4.x * TT + t4.y] + emb[(size_t)(s0 + 1) * TT + t4.y];
    if (m4.z) ns += trans[t4.y * TT + t4.z] + emb[(size_t)(s0 + 2) * TT + t4.z];
    if (m4.w) ns += trans[t4.z * TT + t4.w] + emb[(size_t)(s0 + 3) * TT + t4.w];
    float wsum = wave_sum(ns);
    int wcnt = wave_sum_i(cnt);
    __shared__ float sf[4]; __shared__ int si[4];
    if ((tid & 63) == 0) { sf[tid >> 6] = wsum; si[tid >> 6] = wcnt; }
    __syncthreads();
    if (tid == 0) {
        float tot = sf[0] + sf[1] + sf[2] + sf[3];
        int L = si[0] + si[1] + si[2] + si[3];
        int t0 = tg[0];
        tot += start_tr[t0] + emb[t0] + end_tr[tg[L - 1]];
        numer[b] = tot;
        lenArr[b] = L;
    }
}

// ---------- main: 5 waves/WG. wave0 = MFMA consumer; waves1-4 = 2 producer teams ----------
// f32 ring: entry (slot, row u, section j, lane): float4 = exp(em[t, j*16+q*4 .. +3])
// for batch n, where lane = q*16+n. Producers use the SAME lane mapping
// (nb=lane&15, q4=lane>>4) so both read & write at entry==lane: conflict-free b128.
__global__ __launch_bounds__(320, 1)
void crf_fwd(const float* __restrict__ em, const float* __restrict__ start_tr,
             const float* __restrict__ end_tr, const float* __restrict__ trans,
             const int* __restrict__ lenArr, float* __restrict__ denomArr) {
    __shared__ float4v ring[NSLOT * CK * 3 * 64];   // 98304 B

    const int tid = threadIdx.x;
    const int wave = tid >> 6, lane = tid & 63;
    const int wgbase = blockIdx.x * GG;
    const float4v Zv = {0.f, 0.f, 0.f, 0.f};

    if (wave == 0) {
        // ================= CONSUMER =================
        __builtin_amdgcn_s_setprio(1);   // critical wave: keep issue priority over producers
        const int n = lane & 15, q = lane >> 4;
        const int bb = wgbase + n;

        // A[m=s_out][k-slot(s_in)] = exp(trans[s_out][s_in])
        short8 afr[3][2];
#pragma unroll
        for (int mt = 0; mt < 3; ++mt) {
            const int so = mt * 16 + n;
#pragma unroll
            for (int kt = 0; kt < 2; ++kt) {
                short8 a;
#pragma unroll
                for (int i = 0; i < 8; ++i) {
                    int si_;
                    if (kt == 0) si_ = (i < 4) ? (q * 4 + i) : (16 + q * 4 + (i - 4));
                    else         si_ = (i < 4) ? (32 + q * 4 + i) : -1;
                    a[i] = (si_ >= 0) ? (short)f2bf(__expf(trans[so * TT + si_])) : (short)0;
                }
                afr[mt][kt] = a;
            }
        }

        // init p = exp(start) * exp(em row0)   (state t=0)
        const float* em0 = em + (size_t)bb * SS * TT + q * 4;
        float4v p0, p1, p2;
        {
            float4v v0 = *(const float4v*)(em0);
            float4v v1 = *(const float4v*)(em0 + 16);
            float4v v2 = *(const float4v*)(em0 + 32);
            const int sb = q * 4;
#pragma unroll
            for (int r = 0; r < 4; ++r) {
                p0[r] = __expf(start_tr[sb + r] + v0[r]);
                p1[r] = __expf(start_tr[16 + sb + r] + v1[r]);
                p2[r] = __expf(start_tr[32 + sb + r] + v2[r]);
            }
        }

        const int len = lenArr[bb];
        int Lmax = len;
#pragma unroll
        for (int off = 1; off < 64; off <<= 1) {
            int o = __shfl_xor(Lmax, off, 64);
            Lmax = Lmax > o ? Lmax : o;
        }
        const int P = (Lmax + 6) >> 3;   // ceil((Lmax-1)/8)

        const bool cc0 = (len == 1);
        float4v dc0 = cc0 ? p0 : Zv, dc1 = cc0 ? p1 : Zv, dc2 = cc0 ? p2 : Zv;
        float lcap = 0.f, logscale = 0.f;

        for (int pp = -3; pp < P; ++pp) {
            if (pp >= 0) {
                const float4v* rp = ring + (size_t)(pp % NSLOT) * (CK * 3 * 64) + lane;
                // row 0 of this chunk (ready: producers wrote it last period)
                float4v e0 = rp[0], e1 = rp[64], e2 = rp[128];
                const int lo = 8 * pp + 2, hi = 8 * pp + 9;
                const bool any = __ballot((len >= lo) & (len <= hi)) != 0ull;
#pragma unroll
                for (int u = 0; u < 8; ++u) {
                    // pack B operand from p (state t-1) — only VALU on the chain
                    union { short8 v; unsigned w[4]; } B0, B1;
                    B0.w[0] = pk2bf(p0[0], p0[1]); B0.w[1] = pk2bf(p0[2], p0[3]);
                    B0.w[2] = pk2bf(p1[0], p1[1]); B0.w[3] = pk2bf(p1[2], p1[3]);
                    B1.w[0] = pk2bf(p2[0], p2[1]); B1.w[1] = pk2bf(p2[2], p2[3]);
                    B1.w[2] = 0u; B1.w[3] = 0u;
                    float4v A0 = __builtin_amdgcn_mfma_f32_16x16x32_bf16(afr[0][0], B0.v, Zv, 0, 0, 0);
                    float4v A1 = __builtin_amdgcn_mfma_f32_16x16x32_bf16(afr[1][0], B0.v, Zv, 0, 0, 0);
                    float4v A2 = __builtin_amdgcn_mfma_f32_16x16x32_bf16(afr[2][0], B0.v, Zv, 0, 0, 0);
                    A0 = __builtin_amdgcn_mfma_f32_16x16x32_bf16(afr[0][1], B1.v, A0, 0, 0, 0);
                    A1 = __builtin_amdgcn_mfma_f32_16x16x32_bf16(afr[1][1], B1.v, A1, 0, 0, 0);
                    A2 = __builtin_amdgcn_mfma_f32_16x16x32_bf16(afr[2][1], B1.v, A2, 0, 0, 0);
                    // off-chain: prefetch next row's emissions (f32, used next step)
                    float4v n0, n1, n2;
                    if (u < 7) {
                        n0 = rp[(u + 1) * 192];
                        n1 = rp[(u + 1) * 192 + 64];
                        n2 = rp[(u + 1) * 192 + 128];
                    }
                    // p_t = (M @ p_{t-1}) * exp(em_t)  — vector muls (v_pk_mul_f32 capable)
                    p0 = A0 * e0; p1 = A1 * e1; p2 = A2 * e2;
                    if (any) {
                        const bool cc = (len == 8 * pp + u + 2);   // t = 1 + 8*pp + u
                        dc0 = cc ? p0 : dc0; dc1 = cc ? p1 : dc1; dc2 = cc ? p2 : dc2;
                        lcap = cc ? logscale : lcap;
                    }
                    e0 = n0; e1 = n1; e2 = n2;
                    if (u == 7) {   // renorm once per chunk (VALU-only cross-lane max)
                        float m = fmaxf(fmaxf(p0[0], p0[1]), fmaxf(p0[2], p0[3]));
                        m = fmaxf(m, fmaxf(fmaxf(p1[0], p1[1]), fmaxf(p1[2], p1[3])));
                        m = fmaxf(m, fmaxf(fmaxf(p2[0], p2[1]), fmaxf(p2[2], p2[3])));
                        m = fmaxf(xgrp_max(m), 1e-30f);
                        logscale += __logf(m);
                        const float rm = __builtin_amdgcn_rcpf(m);
                        p0 *= rm; p1 *= rm; p2 *= rm;
                    }
                }
            }
            __builtin_amdgcn_s_barrier();
        }

        // epilogue
        float pe = 0.f;
        {
            const int sb = q * 4;
#pragma unroll
            for (int r = 0; r < 4; ++r) {
                pe = fmaf(dc0[r], __expf(end_tr[sb + r]), pe);
                pe = fmaf(dc1[r], __expf(end_tr[16 + sb + r]), pe);
                pe = fmaf(dc2[r], __expf(end_tr[32 + sb + r]), pe);
            }
        }
        pe = xgrp_sum(pe);
        if (lane < 16) denomArr[bb] = lcap + __logf(pe);

    } else {
        // ================= PRODUCERS (waves 1..4, two teams) =================
        const int T = (wave - 1) >> 1;       // team parity: chunks c with (c&1)==T
        const int sub = (wave - 1) & 1;      // items i = sub*12 .. sub*12+11
        const int nb = lane & 15, q4 = lane >> 4;   // SAME mapping as consumer
        const int bb = wgbase + nb;
        const int len_v = lenArr[bb];
        int Lmax = len_v;
#pragma unroll
        for (int off = 1; off < 64; off <<= 1) {
            int o = __shfl_xor(Lmax, off, 64);
            Lmax = Lmax > o ? Lmax : o;
        }
        const int P = (Lmax + 6) >> 3;

        const float* emP = em + (size_t)bb * SS * TT + q4 * 4;
        float4 buf[12];   // single named buffer, constant indices -> registers
        const float4v Z4 = {0.f, 0.f, 0.f, 0.f};

        for (int pp = -3; pp < P; ++pp) {
            int cv = pp + 1;                 // chunk to convert (loaded 2 periods ago)
            if (cv >= 0 && cv < P && (cv & 1) == T) {
                float4v* wp = ring + (size_t)(cv % NSLOT) * (CK * 3 * 64) + lane;
#pragma unroll
                for (int k = 0; k < 12; ++k) {
                    const int i = sub * 12 + k, u = i / 3, j = i % 3;
                    const int t = 1 + 8 * cv + u;
                    const bool live = t < len_v;
                    float4 v = buf[k];
                    float4v o;
                    o[0] = __expf(v.x); o[1] = __expf(v.y);
                    o[2] = __expf(v.z); o[3] = __expf(v.w);
                    o = live ? o : Z4;
                    wp[(size_t)(u * 3 + j) * 64] = o;
                }
            }
            int ci = pp + 3;                 // chunk to issue loads for (same parity)
            if (ci < P && (ci & 1) == T) {
#pragma unroll
                for (int k = 0; k < 12; ++k) {
                    const int i = sub * 12 + k, u = i / 3, j = i % 3;
                    int t = 1 + 8 * ci + u; t = t < SS ? t : SS - 1;
                    buf[k] = *(const float4*)(emP + (size_t)t * TT + j * 16);
                }
            }
            __builtin_amdgcn_s_waitcnt(0xC07F);  // lgkmcnt(0) only; vmcnt stays in flight
            __builtin_amdgcn_s_barrier();
        }
    }
}

__global__ __launch_bounds__(64)
void crf_reduce(const float* __restrict__ denom, const float* __restrict__ numer,
                float* __restrict__ out) {
    int lane = threadIdx.x;
    float s = 0.f;
    for (int i = lane; i < BB; i += 64) s += denom[i] - numer[i];
    s = wave_sum(s);
    if (lane == 0) out[0] = s * (1.0f / (float)BB);
}

extern "C" void kernel_launch(void* const* d_in, const int* in_sizes, int n_in,
                              void* d_out, int out_size, void* d_ws, size_t ws_size,
                              hipStream_t stream) {
    const float* emissions = (const float*)d_in[0];
    const int*   tags      = (const int*)d_in[1];
    const int*   mask      = (const int*)d_in[2];
    const float* start_tr  = (const float*)d_in[3];
    const float* end_tr    = (const float*)d_in[4];
    const float* trans     = (const float*)d_in[5];

    char* ws = (char*)d_ws;
    float* denom = (float*)ws;               // 512 f32
    float* numer = (float*)(ws + 2048);      // 512 f32
    int*   lenA  = (int*)(ws + 4096);        // 512 i32

    crf_numer<<<BB, 256, 0, stream>>>(emissions, tags, mask, start_tr, end_tr,
                                      trans, numer, lenA);
    crf_fwd<<<BB / GG, 320, 0, stream>>>(emissions, start_tr, end_tr, trans,
                                         lenA, denom);
    crf_reduce<<<1, 64, 0, stream>>>(denom, numer, (float*)d_out);
}